// Round 1
// baseline (884.744 us; speedup 1.0000x reference)
//
#include <hip/hip_runtime.h>
#include <hip/hip_fp16.h>

#define H 256
#define HETD 3
#define AH 128
#define BSEG 64

typedef _Float16 half8 __attribute__((ext_vector_type(8)));
typedef __attribute__((ext_vector_type(4))) float f32x4;

// ---------------------------------------------------------------------------
// Pack W1 [259][128] fp32 -> f16 MFMA B-fragments.
// Layout: frag index ((t*8 + nt)*64 + lane), 8 f16 per lane.
// B[k][n]: n = nt*16 + (lane&15), k = t*32 + (lane>>4)*8 + j, zero-pad k>=259.
// ---------------------------------------------------------------------------
__global__ void pack_w1_kernel(const float* __restrict__ W1,
                               unsigned short* __restrict__ W1p) {
    int idx = blockIdx.x * 256 + threadIdx.x;
    if (idx >= 9 * 8 * 64 * 8) return;
    int j    = idx & 7;
    int lane = (idx >> 3) & 63;
    int nt   = (idx >> 9) & 7;
    int t    = idx >> 12;
    int n = nt * 16 + (lane & 15);
    int k = t * 32 + ((lane >> 4) & 3) * 8 + j;
    float w = (k < (H + HETD)) ? W1[k * AH + n] : 0.f;
    __half hw = __float2half(w);
    W1p[idx] = __half_as_ushort(hw);
}

__device__ __forceinline__ _Float16 f2h(float f) { return (_Float16)f; }

// ---------------------------------------------------------------------------
// Gate MLP: raw_i = tanh([x_i;het_i] @ W1 + b1) @ W2 + b2 ; p_i = exp(raw_i)
// Per-segment denominator d[seg] += p_i (LDS-reduced, then global atomic).
// Each wave handles 64 nodes via 16x16x32 f16 MFMA (M=64 over 4 mtiles,
// N=128 over 8 ntiles, K=288 over 9 ktiles; ktile 8 = het + zero pad).
// ---------------------------------------------------------------------------
__global__ __launch_bounds__(256) void gate_kernel(
    const float* __restrict__ x, const float* __restrict__ het,
    const int* __restrict__ batch, const unsigned short* __restrict__ W1p,
    const float* __restrict__ b1, const float* __restrict__ W2,
    const float* __restrict__ b2, float* __restrict__ p,
    float* __restrict__ d, int n_nodes)
{
    __shared__ float sW2[AH];
    __shared__ float sb1[AH];
    __shared__ float sd[BSEG];
    int tid = threadIdx.x;
    if (tid < AH) { sW2[tid] = W2[tid]; sb1[tid] = b1[tid]; }
    if (tid < BSEG) sd[tid] = 0.f;
    __syncthreads();

    int lane = tid & 63;
    int wv   = tid >> 6;
    int row  = lane & 15;
    int quad = lane >> 4;
    long long base = ((long long)blockIdx.x * 4 + wv) * 64;

    if (base < n_nodes) {
        f32x4 acc[4][8] = {};
        int nodeA[4];
#pragma unroll
        for (int m = 0; m < 4; ++m) {
            long long nd = base + m * 16 + row;
            nodeA[m] = (int)(nd < n_nodes ? nd : (long long)(n_nodes - 1));
        }
        const uint4* W1p4 = (const uint4*)W1p;

        // K-tiles 0..7: the x part (k = 0..255)
        for (int t = 0; t < 8; ++t) {
            half8 a[4];
#pragma unroll
            for (int m = 0; m < 4; ++m) {
                const float4* xr =
                    (const float4*)(x + (size_t)nodeA[m] * H + t * 32 + quad * 8);
                float4 lo = xr[0];
                float4 hi = xr[1];
                half8 av;
                av[0] = f2h(lo.x); av[1] = f2h(lo.y);
                av[2] = f2h(lo.z); av[3] = f2h(lo.w);
                av[4] = f2h(hi.x); av[5] = f2h(hi.y);
                av[6] = f2h(hi.z); av[7] = f2h(hi.w);
                a[m] = av;
            }
#pragma unroll
            for (int nt = 0; nt < 8; ++nt) {
                union { uint4 u; half8 h; } cv;
                cv.u = W1p4[(t * 8 + nt) * 64 + lane];
#pragma unroll
                for (int m = 0; m < 4; ++m)
                    acc[m][nt] = __builtin_amdgcn_mfma_f32_16x16x32_f16(
                        a[m], cv.h, acc[m][nt], 0, 0, 0);
            }
        }
        // K-tile 8: het (k = 256..258) + zero pad
        {
            half8 a[4];
#pragma unroll
            for (int m = 0; m < 4; ++m) {
                half8 av = {0, 0, 0, 0, 0, 0, 0, 0};
                if (quad == 0) {
                    const float* hr = het + (size_t)nodeA[m] * HETD;
                    av[0] = f2h(hr[0]); av[1] = f2h(hr[1]); av[2] = f2h(hr[2]);
                }
                a[m] = av;
            }
#pragma unroll
            for (int nt = 0; nt < 8; ++nt) {
                union { uint4 u; half8 h; } cv;
                cv.u = W1p4[(8 * 8 + nt) * 64 + lane];
#pragma unroll
                for (int m = 0; m < 4; ++m)
                    acc[m][nt] = __builtin_amdgcn_mfma_f32_16x16x32_f16(
                        a[m], cv.h, acc[m][nt], 0, 0, 0);
            }
        }

        // Epilogue: tanh -> @W2 -> exp.  C/D layout: n = nt*16 + (lane&15),
        // node_local = mtile*16 + quad*4 + r.
        float b2v = b2[0];
#pragma unroll
        for (int m = 0; m < 4; ++m) {
#pragma unroll
            for (int r = 0; r < 4; ++r) {
                float partial = 0.f;
#pragma unroll
                for (int nt = 0; nt < 8; ++nt) {
                    int n = nt * 16 + row;
                    float h = acc[m][nt][r] + sb1[n];
                    // tanh(h) = 1 - 2/(e^{2h}+1); inf-safe at both ends
                    float e2 = __expf(2.f * h);
                    partial += (1.f - 2.f / (e2 + 1.f)) * sW2[n];
                }
                // reduce over the 16 lanes of this quad-group (n dimension)
                partial += __shfl_xor(partial, 1);
                partial += __shfl_xor(partial, 2);
                partial += __shfl_xor(partial, 4);
                partial += __shfl_xor(partial, 8);
                long long node = base + m * 16 + quad * 4 + r;
                if (row == r && node < n_nodes) {
                    float pe = __expf(partial + b2v);
                    p[node] = pe;
                    atomicAdd(&sd[batch[node]], pe);
                }
            }
        }
    }
    __syncthreads();
    if (tid < BSEG) {
        float v = sd[tid];
        if (v != 0.f) atomicAdd(&d[tid], v);
    }
}

// ---------------------------------------------------------------------------
// S[seg][k] += p_i * x[i][k].  batch is sorted, so each thread accumulates a
// run in registers and flushes via global atomics only at segment changes.
// Wave = 64 lanes cover one full 256-float row as float4 (perfect coalescing);
// 4 waves stride over nodes.
// ---------------------------------------------------------------------------
__global__ __launch_bounds__(256) void accum_kernel(
    const float* __restrict__ x, const float* __restrict__ p,
    const int* __restrict__ batch, float* __restrict__ S, int n_nodes)
{
    const int TILE = 512;
    int tid = threadIdx.x;
    int c4 = tid & 63;   // which float4 of the row
    int ng = tid >> 6;   // node offset within group of 4
    long long start = (long long)blockIdx.x * TILE;
    long long end = start + TILE;
    if (end > n_nodes) end = n_nodes;
    if (start >= n_nodes) return;

    float ax = 0.f, ay = 0.f, az = 0.f, aw = 0.f;
    int cur = -1;
    for (long long i = start + ng; i < end; i += 4) {
        int sg = batch[i];
        float pi = p[i];
        if (sg != cur) {               // wave-uniform branch (same i per wave)
            if (cur >= 0) {
                float* Sp = S + cur * H + c4 * 4;
                atomicAdd(Sp + 0, ax); atomicAdd(Sp + 1, ay);
                atomicAdd(Sp + 2, az); atomicAdd(Sp + 3, aw);
            }
            cur = sg; ax = ay = az = aw = 0.f;
        }
        float4 xv = ((const float4*)(x + (size_t)i * H))[c4];
        ax += pi * xv.x; ay += pi * xv.y; az += pi * xv.z; aw += pi * xv.w;
    }
    if (cur >= 0) {
        float* Sp = S + cur * H + c4 * 4;
        atomicAdd(Sp + 0, ax); atomicAdd(Sp + 1, ay);
        atomicAdd(Sp + 2, az); atomicAdd(Sp + 3, aw);
    }
}

// ---------------------------------------------------------------------------
// attn_i = p_i / d[batch_i]
// ---------------------------------------------------------------------------
__global__ void attn_kernel(const float* __restrict__ p,
                            const int* __restrict__ batch,
                            const float* __restrict__ d,
                            float* __restrict__ attn, int n_nodes) {
    int i = blockIdx.x * 256 + threadIdx.x;
    if (i < n_nodes) attn[i] = p[i] / d[batch[i]];
}

// ---------------------------------------------------------------------------
// z[b] = (S[b]/d[b]) @ Wv + bv   (empty segment -> 0, matching segsum)
// ---------------------------------------------------------------------------
__global__ __launch_bounds__(256) void z_kernel(
    const float* __restrict__ S, const float* __restrict__ d,
    const float* __restrict__ Wv, const float* __restrict__ bv,
    float* __restrict__ z)
{
    __shared__ float sA[H];
    int b = blockIdx.x;
    int j = threadIdx.x;
    float dv = d[b];
    float inv = (dv != 0.f) ? 1.f / dv : 0.f;
    sA[j] = S[b * H + j] * inv;
    __syncthreads();
    float sum = (dv != 0.f) ? bv[j] : 0.f;
#pragma unroll 4
    for (int h = 0; h < H; ++h)
        sum += sA[h] * Wv[h * H + j];
    z[b * H + j] = sum;
}

extern "C" void kernel_launch(void* const* d_in, const int* in_sizes, int n_in,
                              void* d_out, int out_size, void* d_ws, size_t ws_size,
                              hipStream_t stream)
{
    const float* x   = (const float*)d_in[0];
    const float* het = (const float*)d_in[1];
    const int*   bat = (const int*)d_in[2];
    const float* W1  = (const float*)d_in[3];
    const float* b1  = (const float*)d_in[4];
    const float* W2  = (const float*)d_in[5];
    const float* b2  = (const float*)d_in[6];
    const float* Wv  = (const float*)d_in[7];
    const float* bv  = (const float*)d_in[8];
    int n = in_sizes[0] / H;  // 500000

    // ws layout: d[64] | S[64*256] | p[n] | W1p (f16 frags, 36864 shorts)
    float* wsf = (float*)d_ws;
    float* d_d = wsf;
    float* d_S = wsf + BSEG;
    float* d_p = wsf + BSEG + BSEG * H;
    unsigned short* d_W1p = (unsigned short*)(wsf + BSEG + BSEG * H + n);

    hipMemsetAsync(d_d, 0, (BSEG + BSEG * H) * sizeof(float), stream);
    pack_w1_kernel<<<(9 * 8 * 64 * 8 + 255) / 256, 256, 0, stream>>>(W1, d_W1p);

    int waves = (n + 63) / 64;
    gate_kernel<<<(waves + 3) / 4, 256, 0, stream>>>(x, het, bat, d_W1p,
                                                     b1, W2, b2, d_p, d_d, n);
    accum_kernel<<<(n + 511) / 512, 256, 0, stream>>>(x, d_p, bat, d_S, n);
    attn_kernel<<<(n + 255) / 256, 256, 0, stream>>>(d_p, bat, d_d,
                                                     (float*)d_out + BSEG * H, n);
    z_kernel<<<BSEG, 256, 0, stream>>>(d_S, d_d, Wv, bv, (float*)d_out);
}